// Round 5
// baseline (161.912 us; speedup 1.0000x reference)
//
#include <hip/hip_runtime.h>
#include <math.h>

#define B_ 2
#define F_ 128
#define N_ 192
#define S_ 192
#define NS_ (N_ * S_)          // 36864
#define SLOPE 0.2f
#define LOG2E 1.4426950408889634f
#define NEG_INF (-__builtin_inff())

#if defined(__has_builtin)
#if __has_builtin(__builtin_amdgcn_exp2f)
#define EXP2(x) __builtin_amdgcn_exp2f(x)
#else
#define EXP2(x) exp2f(x)
#endif
#else
#define EXP2(x) exp2f(x)
#endif

__device__ __forceinline__ float lrelu(float e) { return fmaxf(e, SLOPE * e); }

// Workspace layout (float offsets)
#define OFF_WSRC 0             // [f*4+h] * LOG2E
#define OFF_WDST 512
#define OFF_CSRC 1024          // (c_src[h] + b_attn) * LOG2E
#define OFF_CDST 1028
#define OFF_SUMG 1040          // [h*64+d]
#define OFF_PART 1296          // [sq 4][b 2][f 128] xsum partials
#define OFF_SRC  2320          // [bh][i][s], MASKED (-inf where A[s,i]==0)
#define OFF_DST2 (OFF_SRC + 8 * NS_)   // [bh][j][s]
#define OFF_DST1 (OFF_DST2 + 8 * NS_)  // [bh][s][j]

// ---- kPre: blocks 0..1023 xsum partials; 1024: wsrc/wdst; 1025: csrc/cdst ----
__global__ __launch_bounds__(256) void kPre(const float* __restrict__ X,
                                            const float* __restrict__ W_lin,
                                            const float* __restrict__ b_lin,
                                            const float* __restrict__ W_attn,
                                            const float* __restrict__ b_attn,
                                            float* __restrict__ ws) {
    int blk = blockIdx.x, t = threadIdx.x;
    if (blk < 1024) {
        int sq = blk & 3, f = (blk >> 2) & 127, b = blk >> 9;
        const float4* p = (const float4*)(X + ((size_t)(b * F_ + f)) * NS_ + sq * 9216);
        float acc = 0.f;
#pragma unroll
        for (int k = 0; k < 9; k++) {
            float4 v = p[t + k * 256];
            acc += (v.x + v.y) + (v.z + v.w);
        }
        for (int o = 32; o; o >>= 1) acc += __shfl_down(acc, o, 64);
        __shared__ float red[4];
        if ((t & 63) == 0) red[t >> 6] = acc;
        __syncthreads();
        if (t == 0)
            ws[OFF_PART + sq * 256 + b * 128 + f] = (red[0] + red[1]) + (red[2] + red[3]);
    } else if (blk == 1024) {
        const float4* wa = (const float4*)W_attn;
        for (int c = t; c < 512; c += 256) {
            int f = c >> 2, h = c & 3;
            const float4* wl = (const float4*)(W_lin + f * 256 + h * 64);
            float as = 0.f, ad = 0.f;
#pragma unroll
            for (int q = 0; q < 16; q++) {
                float4 w = wl[q], a1 = wa[q], a2 = wa[16 + q];
                as += w.x * a1.x + w.y * a1.y + w.z * a1.z + w.w * a1.w;
                ad += w.x * a2.x + w.y * a2.y + w.z * a2.z + w.w * a2.w;
            }
            ws[OFF_WSRC + c] = as * LOG2E;
            ws[OFF_WDST + c] = ad * LOG2E;
        }
    } else {
        if (t < 4) {
            float c = 0.f;
            for (int d = 0; d < 64; d++) c += b_lin[t * 64 + d] * W_attn[d];
            ws[OFF_CSRC + t] = (c + b_attn[0]) * LOG2E;
        } else if (t < 8) {
            int h = t - 4;
            float c = 0.f;
            for (int d = 0; d < 64; d++) c += b_lin[h * 64 + d] * W_attn[64 + d];
            ws[OFF_CDST + h] = c * LOG2E;
        }
    }
}

// ---- kProj: blocks < 1152: (n, b, s-chunk of 64); block 1152: sum_g ----
__global__ __launch_bounds__(256) void kProj(const float* __restrict__ X,
                                             const int* __restrict__ A,
                                             const float* __restrict__ W_lin,
                                             const float* __restrict__ b_lin,
                                             float* __restrict__ ws) {
    __shared__ float4 wsl[128], wdl[128];
    __shared__ float red[4 * 64 * 9];     // [fq][lane][8 +1 pad]
    __shared__ float xs[128];
    __shared__ float wbuf[4096];
    int t = threadIdx.x, blk = blockIdx.x;
    if (blk < 1152) {
        int n = blk % 192, bsc = blk / 192;
        int b = bsc / 3, sc = bsc % 3;
        if (t < 128) {
            wsl[t] = ((const float4*)(ws + OFF_WSRC))[t];
            wdl[t] = ((const float4*)(ws + OFF_WDST))[t];
        }
        __syncthreads();
        int fq = t >> 6, lane = t & 63;
        int s = sc * 64 + lane;
        float aS[4] = {0, 0, 0, 0}, aD[4] = {0, 0, 0, 0};
        const float* xp = X + (size_t)(b * F_) * NS_ + n * S_ + s;
        int f0 = fq * 32;
#pragma unroll 8
        for (int fi = 0; fi < 32; fi++) {
            float x = xp[(size_t)(f0 + fi) * NS_];
            float4 w1 = wsl[f0 + fi], w2 = wdl[f0 + fi];
            aS[0] += x * w1.x; aS[1] += x * w1.y; aS[2] += x * w1.z; aS[3] += x * w1.w;
            aD[0] += x * w2.x; aD[1] += x * w2.y; aD[2] += x * w2.z; aD[3] += x * w2.w;
        }
        float* rp = red + t * 9;
#pragma unroll
        for (int h = 0; h < 4; h++) { rp[h] = aS[h]; rp[4 + h] = aD[h]; }
        __syncthreads();
        // 512 cells: [k 8][s_loc 64] -> lanes sweep s contiguously (coalesced)
#pragma unroll
        for (int c = t; c < 512; c += 256) {
            int k = c >> 6, s_loc = c & 63;
            float v = red[s_loc * 9 + k] + red[(64 + s_loc) * 9 + k] +
                      red[(128 + s_loc) * 9 + k] + red[(192 + s_loc) * 9 + k];
            int ss = sc * 64 + s_loc;
            if (k < 4) {
                int bh = b * 4 + k;
                bool masked = (A[ss * 192 + n] == 0);   // mask = A[s, i=n]
                ws[OFF_SRC + bh * NS_ + n * 192 + ss] =
                    masked ? NEG_INF : (v + ws[OFF_CSRC + k]);
            } else {
                int h = k - 4, bh = b * 4 + h;
                float dv = v + ws[OFF_CDST + h];
                ws[OFF_DST2 + bh * NS_ + n * 192 + ss] = dv;
                ws[OFF_DST1 + bh * NS_ + ss * 192 + n] = dv;  // scatter, L2
            }
        }
    } else {
        // sum_g[c] = sum_f xsum[f] * W_lin[f][c] + 73728 * b_lin[c]
        if (t < 128) {
            float v = 0.f;
#pragma unroll
            for (int q = 0; q < 8; q++) v += ws[OFF_PART + q * 128 + t];
            xs[t] = v;
        }
        float acc = 0.f;
        for (int ch = 0; ch < 8; ch++) {
            const float4* s4 = (const float4*)(W_lin + ch * 4096);
            __syncthreads();
#pragma unroll
            for (int k = 0; k < 4; k++) ((float4*)wbuf)[t + k * 256] = s4[t + k * 256];
            __syncthreads();
#pragma unroll
            for (int fi = 0; fi < 16; fi++) acc += xs[ch * 16 + fi] * wbuf[fi * 256 + t];
        }
        ws[OFF_SUMG + t] = acc + 73728.f * b_lin[t];
    }
}

// ---- kAttn: 768 blocks (bh = blk&7 XCD swizzle, 2 i rows), 384 thr, float4 I/O ----
__global__ __launch_bounds__(384) void kAttn(const float* __restrict__ ws,
                                             float* __restrict__ out) {
    int blk = blockIdx.x, t = threadIdx.x;
    int bh = blk & 7, iq = blk >> 3;        // iq 0..95
    int b = bh >> 2, h = bh & 3;
    __shared__ float p_sh[384];             // [i2][s192]
    __shared__ float zpart[16 * 192];       // passA: [sq8][i2][j192]; passB: [jq4][i2][s4 48]x4
    __shared__ float zr_sh[384];            // [i2][j192]
    __shared__ float alpha_sh[384];         // [i2][s192]
    __shared__ float sg_sh[64];
    const float* src = ws + OFF_SRC + bh * NS_;
    const float* d1 = ws + OFF_DST1 + bh * NS_;
    const float* d2 = ws + OFF_DST2 + bh * NS_;
    if (t < 64) sg_sh[t] = ws[OFF_SUMG + h * 64 + t];
    p_sh[t] = src[iq * 384 + t];            // 2 contiguous i-rows
    __syncthreads();

    // Pass A: Z[i][j] partials; thread = (s-chunk of 24, j-quad), float4 along j
    {
        int sq = t / 48, j4 = t % 48;
        float4 a0 = make_float4(0.f, 0.f, 0.f, 0.f);
        float4 a1 = make_float4(0.f, 0.f, 0.f, 0.f);
        const float* base = d1 + j4 * 4;
        int s0 = sq * 24;
#pragma unroll 4
        for (int s = s0; s < s0 + 24; s++) {
            float4 q = *(const float4*)(base + s * 192);
            float p0 = p_sh[s], p1 = p_sh[192 + s];
            a0.x += EXP2(lrelu(p0 + q.x)); a0.y += EXP2(lrelu(p0 + q.y));
            a0.z += EXP2(lrelu(p0 + q.z)); a0.w += EXP2(lrelu(p0 + q.w));
            a1.x += EXP2(lrelu(p1 + q.x)); a1.y += EXP2(lrelu(p1 + q.y));
            a1.z += EXP2(lrelu(p1 + q.z)); a1.w += EXP2(lrelu(p1 + q.w));
        }
        *(float4*)&zpart[(sq * 2 + 0) * 192 + j4 * 4] = a0;
        *(float4*)&zpart[(sq * 2 + 1) * 192 + j4 * 4] = a1;
    }
    __syncthreads();
    {
        int i_loc = t / 192, j = t % 192;
        float Z = 0.f;
#pragma unroll
        for (int sq = 0; sq < 8; sq++) Z += zpart[(sq * 2 + i_loc) * 192 + j];
        zr_sh[i_loc * 192 + j] = (Z != 0.f) ? (1.f / Z) : 0.f;  // all-masked col -> 0
    }
    __syncthreads();

    // Pass B: alpha[i][s]; thread = (j-quarter, i, s-quad), float4 along s
    {
        int jq = t / 96, rem = t % 96;
        int i_loc = rem / 48, s4 = rem % 48;
        float4 pv = *(const float4*)&p_sh[i_loc * 192 + s4 * 4];
        const float* zr = zr_sh + i_loc * 192;
        const float* base = d2 + s4 * 4;
        float4 acc = make_float4(0.f, 0.f, 0.f, 0.f);
        int j0 = jq * 48;
#pragma unroll 4
        for (int j = j0; j < j0 + 48; j++) {
            float4 q = *(const float4*)(base + j * 192);
            float z = zr[j];
            acc.x += EXP2(lrelu(pv.x + q.x)) * z;
            acc.y += EXP2(lrelu(pv.y + q.y)) * z;
            acc.z += EXP2(lrelu(pv.z + q.z)) * z;
            acc.w += EXP2(lrelu(pv.w + q.w)) * z;
        }
        __syncthreads();   // zpart reuse
        *(float4*)&zpart[((jq * 2 + i_loc) * 48 + s4) * 4] = acc;
    }
    __syncthreads();
    {
        int i_loc = t / 192, s = t % 192;
        int s4 = s >> 2, c = s & 3;
        float al = 0.f;
#pragma unroll
        for (int jq = 0; jq < 4; jq++) al += zpart[((jq * 2 + i_loc) * 48 + s4) * 4 + c];
        alpha_sh[t] = al;
    }
    __syncthreads();

    // Epilogue: thread = (d-quarter, i, s-quad), float4 stores
    {
        int dq = t / 96, rem = t % 96;
        int i_loc = rem / 48, s4 = rem % 48;
        float4 al = *(const float4*)&alpha_sh[i_loc * 192 + s4 * 4];
        int i = iq * 2 + i_loc;
        float* op = out + (((size_t)(b * 256 + h * 64 + dq * 16)) * 192 + i) * 192 + s4 * 4;
#pragma unroll 4
        for (int d = 0; d < 16; d++) {
            float g = sg_sh[dq * 16 + d];
            float4 o = make_float4(al.x * g, al.y * g, al.z * g, al.w * g);
            *(float4*)(op + (size_t)d * NS_) = o;
        }
    }
}

extern "C" void kernel_launch(void* const* d_in, const int* in_sizes, int n_in,
                              void* d_out, int out_size, void* d_ws, size_t ws_size,
                              hipStream_t stream) {
    const float* X      = (const float*)d_in[0];
    const int*   A      = (const int*)d_in[1];
    const float* W_lin  = (const float*)d_in[2];
    const float* b_lin  = (const float*)d_in[3];
    const float* W_attn = (const float*)d_in[4];
    const float* b_attn = (const float*)d_in[5];
    float* out = (float*)d_out;
    float* ws  = (float*)d_ws;

    kPre<<<1026, 256, 0, stream>>>(X, W_lin, b_lin, W_attn, b_attn, ws);
    kProj<<<1153, 256, 0, stream>>>(X, A, W_lin, b_lin, ws);
    kAttn<<<768, 384, 0, stream>>>(ws, out);
}

// Round 6
// 156.161 us; speedup vs baseline: 1.0368x; 1.0368x over previous
//
#include <hip/hip_runtime.h>
#include <math.h>

#define B_ 2
#define F_ 128
#define N_ 192
#define S_ 192
#define NS_ (N_ * S_)          // 36864
#define SLOPE 0.2f
#define LOG2E 1.4426950408889634f
#define NEG_INF (-__builtin_inff())

#if defined(__has_builtin)
#if __has_builtin(__builtin_amdgcn_exp2f)
#define EXP2(x) __builtin_amdgcn_exp2f(x)
#else
#define EXP2(x) exp2f(x)
#endif
#else
#define EXP2(x) exp2f(x)
#endif

__device__ __forceinline__ float lrelu(float e) { return fmaxf(e, SLOPE * e); }

// Workspace layout (float offsets)
#define OFF_WSRC 0             // [f*4+h] * LOG2E
#define OFF_WDST 512
#define OFF_CSRC 1024          // (c_src[h] + b_attn) * LOG2E
#define OFF_CDST 1028
#define OFF_SUMG 1040          // [h*64+d]
#define OFF_PART 1296          // [sq 4][b 2][f 128] xsum partials
#define OFF_SRC  2320          // [bh][i][s], MASKED (-inf where A[s,i]==0)
#define OFF_DST2 (OFF_SRC + 8 * NS_)    // [bh][j][s]
#define OFF_DST1 (OFF_DST2 + 8 * NS_)   // [bh][s][j]
#define OFF_ALPHA (OFF_DST1 + 8 * NS_)  // [bh][i][s]

// ---- kPre: blocks 0..1023 xsum partials; 1024: wsrc/wdst; 1025: csrc/cdst ----
__global__ __launch_bounds__(256) void kPre(const float* __restrict__ X,
                                            const float* __restrict__ W_lin,
                                            const float* __restrict__ b_lin,
                                            const float* __restrict__ W_attn,
                                            const float* __restrict__ b_attn,
                                            float* __restrict__ ws) {
    int blk = blockIdx.x, t = threadIdx.x;
    if (blk < 1024) {
        int sq = blk & 3, f = (blk >> 2) & 127, b = blk >> 9;
        const float4* p = (const float4*)(X + ((size_t)(b * F_ + f)) * NS_ + sq * 9216);
        float acc = 0.f;
#pragma unroll
        for (int k = 0; k < 9; k++) {
            float4 v = p[t + k * 256];
            acc += (v.x + v.y) + (v.z + v.w);
        }
        for (int o = 32; o; o >>= 1) acc += __shfl_down(acc, o, 64);
        __shared__ float red[4];
        if ((t & 63) == 0) red[t >> 6] = acc;
        __syncthreads();
        if (t == 0)
            ws[OFF_PART + sq * 256 + b * 128 + f] = (red[0] + red[1]) + (red[2] + red[3]);
    } else if (blk == 1024) {
        const float4* wa = (const float4*)W_attn;
        for (int c = t; c < 512; c += 256) {
            int f = c >> 2, h = c & 3;
            const float4* wl = (const float4*)(W_lin + f * 256 + h * 64);
            float as = 0.f, ad = 0.f;
#pragma unroll
            for (int q = 0; q < 16; q++) {
                float4 w = wl[q], a1 = wa[q], a2 = wa[16 + q];
                as += w.x * a1.x + w.y * a1.y + w.z * a1.z + w.w * a1.w;
                ad += w.x * a2.x + w.y * a2.y + w.z * a2.z + w.w * a2.w;
            }
            ws[OFF_WSRC + c] = as * LOG2E;
            ws[OFF_WDST + c] = ad * LOG2E;
        }
    } else {
        if (t < 4) {
            float c = 0.f;
            for (int d = 0; d < 64; d++) c += b_lin[t * 64 + d] * W_attn[d];
            ws[OFF_CSRC + t] = (c + b_attn[0]) * LOG2E;
        } else if (t < 8) {
            int h = t - 4;
            float c = 0.f;
            for (int d = 0; d < 64; d++) c += b_lin[h * 64 + d] * W_attn[64 + d];
            ws[OFF_CDST + h] = c * LOG2E;
        }
    }
}

// ---- kProj: blocks < 1152: (n, b, s-chunk of 64); block 1152: sum_g ----
__global__ __launch_bounds__(256) void kProj(const float* __restrict__ X,
                                             const int* __restrict__ A,
                                             const float* __restrict__ W_lin,
                                             const float* __restrict__ b_lin,
                                             float* __restrict__ ws) {
    __shared__ float4 wsl[128], wdl[128];
    __shared__ float red[4 * 64 * 9];     // [fq][lane][8 +1 pad]
    __shared__ float xs[128];
    __shared__ float wbuf[4096];
    int t = threadIdx.x, blk = blockIdx.x;
    if (blk < 1152) {
        int n = blk % 192, bsc = blk / 192;
        int b = bsc / 3, sc = bsc % 3;
        if (t < 128) {
            wsl[t] = ((const float4*)(ws + OFF_WSRC))[t];
            wdl[t] = ((const float4*)(ws + OFF_WDST))[t];
        }
        __syncthreads();
        int fq = t >> 6, lane = t & 63;
        int s = sc * 64 + lane;
        float aS[4] = {0, 0, 0, 0}, aD[4] = {0, 0, 0, 0};
        const float* xp = X + (size_t)(b * F_) * NS_ + n * S_ + s;
        int f0 = fq * 32;
#pragma unroll 8
        for (int fi = 0; fi < 32; fi++) {
            float x = xp[(size_t)(f0 + fi) * NS_];
            float4 w1 = wsl[f0 + fi], w2 = wdl[f0 + fi];
            aS[0] += x * w1.x; aS[1] += x * w1.y; aS[2] += x * w1.z; aS[3] += x * w1.w;
            aD[0] += x * w2.x; aD[1] += x * w2.y; aD[2] += x * w2.z; aD[3] += x * w2.w;
        }
        float* rp = red + t * 9;
#pragma unroll
        for (int h = 0; h < 4; h++) { rp[h] = aS[h]; rp[4 + h] = aD[h]; }
        __syncthreads();
        // 512 cells: [k 8][s_loc 64] -> lanes sweep s contiguously (coalesced)
#pragma unroll
        for (int c = t; c < 512; c += 256) {
            int k = c >> 6, s_loc = c & 63;
            float v = red[s_loc * 9 + k] + red[(64 + s_loc) * 9 + k] +
                      red[(128 + s_loc) * 9 + k] + red[(192 + s_loc) * 9 + k];
            int ss = sc * 64 + s_loc;
            if (k < 4) {
                int bh = b * 4 + k;
                bool masked = (A[ss * 192 + n] == 0);   // mask = A[s, i=n]
                ws[OFF_SRC + bh * NS_ + n * 192 + ss] =
                    masked ? NEG_INF : (v + ws[OFF_CSRC + k]);
            } else {
                int h = k - 4, bh = b * 4 + h;
                float dv = v + ws[OFF_CDST + h];
                ws[OFF_DST2 + bh * NS_ + n * 192 + ss] = dv;
                ws[OFF_DST1 + bh * NS_ + ss * 192 + n] = dv;  // scatter, L2
            }
        }
    } else {
        // sum_g[c] = sum_f xsum[f] * W_lin[f][c] + 73728 * b_lin[c]
        if (t < 128) {
            float v = 0.f;
#pragma unroll
            for (int q = 0; q < 8; q++) v += ws[OFF_PART + q * 128 + t];
            xs[t] = v;
        }
        float acc = 0.f;
        for (int ch = 0; ch < 8; ch++) {
            const float4* s4 = (const float4*)(W_lin + ch * 4096);
            __syncthreads();
#pragma unroll
            for (int k = 0; k < 4; k++) ((float4*)wbuf)[t + k * 256] = s4[t + k * 256];
            __syncthreads();
#pragma unroll
            for (int fi = 0; fi < 16; fi++) acc += xs[ch * 16 + fi] * wbuf[fi * 256 + t];
        }
        ws[OFF_SUMG + t] = acc + 73728.f * b_lin[t];
    }
}

// ---- kAlpha: 768 blocks (bh = blk&7 XCD swizzle, 2 i rows), 384 thr ----
// Computes alpha[bh][i][s]; NO output epilogue (done by kOut).
__global__ __launch_bounds__(384) void kAlpha(float* __restrict__ ws) {
    int blk = blockIdx.x, t = threadIdx.x;
    int bh = blk & 7, iq = blk >> 3;        // iq 0..95
    __shared__ float p_sh[384];             // [i2][s192]
    __shared__ float zpart[2 * 384];        // [sq][i2][j192]
    __shared__ float zr_sh[384];            // [i2][j192]
    const float* src = ws + OFF_SRC + bh * NS_;
    const float* d1 = ws + OFF_DST1 + bh * NS_;
    const float* d2 = ws + OFF_DST2 + bh * NS_;
    p_sh[t] = src[iq * 384 + t];            // 2 contiguous i-rows
    __syncthreads();

    // Pass A: Z[i][j], s split in halves of 96 (coalesced 256B/wave reads)
    {
        int sq = t / 192, j = t - sq * 192;
        float z0 = 0.f, z1 = 0.f;
        const float* d1p = d1 + j;
#pragma unroll 8
        for (int s = sq * 96; s < sq * 96 + 96; s++) {
            float q = d1p[s * 192];
            z0 += EXP2(lrelu(p_sh[s] + q));
            z1 += EXP2(lrelu(p_sh[192 + s] + q));
        }
        zpart[sq * 384 + j] = z0;
        zpart[sq * 384 + 192 + j] = z1;
    }
    __syncthreads();
    {
        float Z = zpart[t] + zpart[384 + t];
        zr_sh[t] = (Z != 0.f) ? (1.f / Z) : 0.f;   // all-masked column -> 0
    }
    __syncthreads();

    // Pass B: alpha[i][s] = sum_j exp2(E[s,j]) * zr[j]; coalesced d2 reads
    {
        int i_loc = t / 192, s = t - i_loc * 192;
        float pv = p_sh[t];
        const float* zr = zr_sh + i_loc * 192;
        float acc = 0.f;
#pragma unroll 8
        for (int j = 0; j < 192; j++) {
            float q = d2[j * 192 + s];
            acc += EXP2(lrelu(pv + q)) * zr[j];
        }
        int i = iq * 2 + i_loc;
        ws[OFF_ALPHA + bh * NS_ + i * 192 + s] = acc;
    }
}

// ---- kOut: pure broadcast write stream: out[b][h*64+d][i][s] = alpha * sum_g ----
__global__ __launch_bounds__(256) void kOut(const float* __restrict__ ws,
                                            float* __restrict__ out) {
    __shared__ float sg[256];
    int t = threadIdx.x;
    sg[t] = ws[OFF_SUMG + t];
    __syncthreads();
    int v = blockIdx.x * 256 + t;           // 294912 threads
    int s4 = v % 48;
    int u = v / 48;
    int i = u % 192; u /= 192;
    int dq = u & 3;  u >>= 2;
    int h = u & 3;
    int b = u >> 2;
    int bh = (b << 2) | h;
    float4 al = *(const float4*)(ws + OFF_ALPHA + (bh * 192 + i) * 192 + s4 * 4);
    float* op = out + (((size_t)(b * 256 + h * 64 + dq * 16)) * 192 + i) * 192 + s4 * 4;
    const float* sgp = sg + h * 64 + dq * 16;
#pragma unroll
    for (int d = 0; d < 16; d++) {
        float g = sgp[d];
        float4 o = make_float4(al.x * g, al.y * g, al.z * g, al.w * g);
        *(float4*)(op + (size_t)d * NS_) = o;
    }
}

extern "C" void kernel_launch(void* const* d_in, const int* in_sizes, int n_in,
                              void* d_out, int out_size, void* d_ws, size_t ws_size,
                              hipStream_t stream) {
    const float* X      = (const float*)d_in[0];
    const int*   A      = (const int*)d_in[1];
    const float* W_lin  = (const float*)d_in[2];
    const float* b_lin  = (const float*)d_in[3];
    const float* W_attn = (const float*)d_in[4];
    const float* b_attn = (const float*)d_in[5];
    float* out = (float*)d_out;
    float* ws  = (float*)d_ws;

    kPre<<<1026, 256, 0, stream>>>(X, W_lin, b_lin, W_attn, b_attn, ws);
    kProj<<<1153, 256, 0, stream>>>(X, A, W_lin, b_lin, ws);
    kAlpha<<<768, 384, 0, stream>>>(ws);
    kOut<<<1152, 256, 0, stream>>>(ws, out);
}